// Round 1
// baseline (25486.919 us; speedup 1.0000x reference)
//
#include <hip/hip_runtime.h>
#include <hip/hip_bf16.h>

// Problem constants
#define LAYERS 12
#define NH     12
#define D      768
#define DH     64
#define FF     3072
#define CTXLEN 1536
#define NS     8
#define NV     1024
#define BB     2
#define TT     1024
#define BT     (BB*TT)          // 2048 token rows

// ---------------------------------------------------------------- utilities
__device__ __forceinline__ float wave_sum(float v) {
    v += __shfl_xor(v, 1);
    v += __shfl_xor(v, 2);
    v += __shfl_xor(v, 4);
    v += __shfl_xor(v, 8);
    v += __shfl_xor(v, 16);
    v += __shfl_xor(v, 32);
    return v;
}

// ---------------------------------------------------------------- embedding
// x[b,t,:] = sum_s rvq[s, tok[b,t,s], :] + pos_embed[positions[b,t], :] + intent[b,0,:]
__global__ __launch_bounds__(256) void embed_kernel(
    const int* __restrict__ prev_tokens, const int* __restrict__ positions,
    const float* __restrict__ intent, const float* __restrict__ rvq,
    const float* __restrict__ pos_emb, float* __restrict__ x) {
    const int row = blockIdx.x;             // 0..2047  (b*1024 + t)
    const int b   = row >> 10;
    __shared__ int toks[NS];
    __shared__ int p;
    if (threadIdx.x < NS) toks[threadIdx.x] = prev_tokens[row * NS + threadIdx.x];
    if (threadIdx.x == NS) p = positions[row];
    __syncthreads();
    for (int d = threadIdx.x; d < D; d += 256) {
        float acc = intent[b * D + d] + pos_emb[p * D + d];
        #pragma unroll
        for (int s = 0; s < NS; ++s)
            acc += rvq[((size_t)(s * NV + toks[s])) * D + d];
        x[(size_t)row * D + d] = acc;
    }
}

// ---------------------------------------------------------------- rmsnorm (per row)
__global__ __launch_bounds__(256) void rmsnorm_kernel(
    const float* __restrict__ x, const float* __restrict__ w, float* __restrict__ h) {
    const int row = blockIdx.x;
    const float* xr = x + (size_t)row * D;
    float ss = 0.f;
    for (int d = threadIdx.x; d < D; d += 256) { float v = xr[d]; ss += v * v; }
    const int wave = threadIdx.x >> 6, lane = threadIdx.x & 63;
    __shared__ float red[4];
    float s = wave_sum(ss);
    if (lane == 0) red[wave] = s;
    __syncthreads();
    float tot = red[0] + red[1] + red[2] + red[3];
    float inv = rsqrtf(tot * (1.0f / D) + 1e-6f);
    for (int d = threadIdx.x; d < D; d += 256)
        h[(size_t)row * D + d] = xr[d] * inv * w[d];
}

// ---------------------------------------------------------------- tiled SGEMM
// C(MxN) = A(MxK) @ W(NxK)^T   (weights are (out,in) row-major, per reference einsum)
// MODE 0: C = acc      MODE 1: scatter qkv -> [3][B,H,T,DH]      MODE 2: C += acc
#define BM 64
#define BN 64
#define BKK 16
template <int MODE>
__global__ __launch_bounds__(256) void gemm_kernel(
    const float* __restrict__ A, const float* __restrict__ W,
    float* __restrict__ C, int M, int N, int K) {
    __shared__ float As[BKK][BM + 1];
    __shared__ float Ws[BKK][BN + 1];
    const int tid = threadIdx.x;
    const int tx = tid & 15, ty = tid >> 4;
    const int row0 = blockIdx.y * BM;
    const int col0 = blockIdx.x * BN;
    float acc[4][4] = {};
    const int m_l = tid >> 2;
    const int kq  = (tid & 3) * 4;
    for (int k0 = 0; k0 < K; k0 += BKK) {
        float4 av = *(const float4*)(A + (size_t)(row0 + m_l) * K + k0 + kq);
        float4 wv = *(const float4*)(W + (size_t)(col0 + m_l) * K + k0 + kq);
        As[kq + 0][m_l] = av.x; As[kq + 1][m_l] = av.y;
        As[kq + 2][m_l] = av.z; As[kq + 3][m_l] = av.w;
        Ws[kq + 0][m_l] = wv.x; Ws[kq + 1][m_l] = wv.y;
        Ws[kq + 2][m_l] = wv.z; Ws[kq + 3][m_l] = wv.w;
        __syncthreads();
        #pragma unroll
        for (int k = 0; k < BKK; ++k) {
            float a[4], bb[4];
            #pragma unroll
            for (int i = 0; i < 4; ++i) a[i] = As[k][ty * 4 + i];
            #pragma unroll
            for (int j = 0; j < 4; ++j) bb[j] = Ws[k][tx * 4 + j];
            #pragma unroll
            for (int i = 0; i < 4; ++i)
                #pragma unroll
                for (int j = 0; j < 4; ++j)
                    acc[i][j] = fmaf(a[i], bb[j], acc[i][j]);
        }
        __syncthreads();
    }
    #pragma unroll
    for (int i = 0; i < 4; ++i) {
        const int m = row0 + ty * 4 + i;
        #pragma unroll
        for (int j = 0; j < 4; ++j) {
            const int n = col0 + tx * 4 + j;
            if (MODE == 0) {
                C[(size_t)m * N + n] = acc[i][j];
            } else if (MODE == 2) {
                C[(size_t)m * N + n] += acc[i][j];
            } else { // qkv scatter: n -> (which, h, d); m -> (b, t)
                const int wsel = n / D;
                const int r = n - wsel * D;
                const int hh = r >> 6, dd = r & 63;
                const int b = m >> 10, t = m & 1023;
                C[(size_t)wsel * (BT * D) + (((size_t)(b * NH + hh)) * TT + t) * DH + dd] = acc[i][j];
            }
        }
    }
}

// ---------------------------------------------------------------- attention
// qkv layout: [3][B,H,T,DH]; one wave per query row, 4 rows per block.
__global__ __launch_bounds__(256) void attn_kernel(
    const float* __restrict__ qkv, float* __restrict__ o) {
    const int bh = blockIdx.y;              // 0..23
    const int b = bh / NH, h = bh - b * NH;
    const int wave = threadIdx.x >> 6, lane = threadIdx.x & 63;
    const int q_idx = blockIdx.x * 4 + wave;
    const float* Q = qkv + (size_t)bh * TT * DH;
    const float* K = qkv + (size_t)BT * D + (size_t)bh * TT * DH;
    const float* V = qkv + 2 * (size_t)BT * D + (size_t)bh * TT * DH;

    const float qv = Q[(size_t)q_idx * DH + lane] * 0.125f;  // fold 1/sqrt(64)
    float acc = 0.f, m = -INFINITY, l = 0.f;

    __shared__ float Ks[64][65];
    __shared__ float Vs[64][65];
    const int kmax = blockIdx.x * 4 + 3;    // largest q in this block
    for (int k0 = 0; k0 <= kmax; k0 += 64) {
        __syncthreads();
        for (int i = threadIdx.x; i < 64 * 64; i += 256) {
            const int r = i >> 6, c = i & 63;
            Ks[r][c] = K[(size_t)(k0 + r) * DH + c];
            Vs[r][c] = V[(size_t)(k0 + r) * DH + c];
        }
        __syncthreads();
        const int lim = min(64, q_idx - k0 + 1);
        for (int kk = 0; kk < lim; ++kk) {
            float s = wave_sum(qv * Ks[kk][lane]);
            const float m_new = fmaxf(m, s);
            const float alpha = __expf(m - m_new);
            const float p = __expf(s - m_new);
            acc = acc * alpha + p * Vs[kk][lane];
            l = l * alpha + p;
            m = m_new;
        }
    }
    // write O as (B,T,H,DH) == (B,T,D)
    o[(((size_t)(b * TT + q_idx)) * NH + h) * DH + lane] = acc / l;
}

// ---------------------------------------------------------------- silu(g)*u -> g
__global__ __launch_bounds__(256) void silu_mul_kernel(
    float* __restrict__ g, const float* __restrict__ u, int n) {
    const int i = blockIdx.x * 256 + threadIdx.x;
    if (i < n) {
        const float gv = g[i], uv = u[i];
        g[i] = gv / (1.f + __expf(-gv)) * uv;
    }
}

// ---------------------------------------------------------------- final norm on last tokens
__global__ __launch_bounds__(256) void final_norm_kernel(
    const float* __restrict__ x, const float* __restrict__ w, float* __restrict__ last) {
    const int b = blockIdx.x;  // 0..1
    const float* xr = x + ((size_t)(b * TT + (TT - 1))) * D;
    float ss = 0.f;
    for (int d = threadIdx.x; d < D; d += 256) { float v = xr[d]; ss += v * v; }
    const int wave = threadIdx.x >> 6, lane = threadIdx.x & 63;
    __shared__ float red[4];
    float s = wave_sum(ss);
    if (lane == 0) red[wave] = s;
    __syncthreads();
    float tot = red[0] + red[1] + red[2] + red[3];
    float inv = rsqrtf(tot * (1.0f / D) + 1e-6f);
    for (int d = threadIdx.x; d < D; d += 256)
        last[(size_t)b * D + d] = xr[d] * inv * w[d];
}

// ---------------------------------------------------------------- heads
// logits[s,b,v] = dot(last[b,:], heads_w[s,v,:]); one wave per (s,v), both b at once
__global__ __launch_bounds__(256) void heads_kernel(
    const float* __restrict__ last, const float* __restrict__ hw, float* __restrict__ out) {
    const int gw = (blockIdx.x * 256 + threadIdx.x) >> 6;   // 0..8191
    const int lane = threadIdx.x & 63;
    const int s = gw >> 10, v = gw & 1023;
    const float* w = hw + (size_t)gw * D;
    float a0 = 0.f, a1 = 0.f;
    for (int d = lane; d < D; d += 64) {
        const float ww = w[d];
        a0 = fmaf(ww, last[d], a0);
        a1 = fmaf(ww, last[D + d], a1);
    }
    a0 = wave_sum(a0);
    a1 = wave_sum(a1);
    if (lane == 0) {
        out[((size_t)s * BB + 0) * NV + v] = a0;
        out[((size_t)s * BB + 1) * NV + v] = a1;
    }
}

// ---------------------------------------------------------------- launcher
extern "C" void kernel_launch(void* const* d_in, const int* in_sizes, int n_in,
                              void* d_out, int out_size, void* d_ws, size_t ws_size,
                              hipStream_t stream) {
    const int*   prev_tokens = (const int*)  d_in[0];
    const int*   positions   = (const int*)  d_in[1];
    const float* intent      = (const float*)d_in[2];
    const float* rvq         = (const float*)d_in[3];
    const float* pos_emb     = (const float*)d_in[4];
    const float* norm1_w     = (const float*)d_in[5];
    const float* norm2_w     = (const float*)d_in[6];
    const float* qkv_w       = (const float*)d_in[7];
    const float* proj_w      = (const float*)d_in[8];
    const float* gate_w      = (const float*)d_in[9];
    const float* up_w        = (const float*)d_in[10];
    const float* down_w      = (const float*)d_in[11];
    const float* normf_w     = (const float*)d_in[12];
    const float* heads_w     = (const float*)d_in[13];
    float* out = (float*)d_out;

    float* ws = (float*)d_ws;
    const size_t XD = (size_t)BT * D;       // 1,572,864
    float* x    = ws;
    float* h    = ws + XD;
    float* qkv  = ws + 2 * XD;              // 3*XD
    float* o    = ws + 5 * XD;
    float* g    = ws + 6 * XD;              // BT*FF
    float* u    = g + (size_t)BT * FF;
    float* last = u + (size_t)BT * FF;      // 2*D

    embed_kernel<<<BT, 256, 0, stream>>>(prev_tokens, positions, intent, rvq, pos_emb, x);

    for (int l = 0; l < LAYERS; ++l) {
        rmsnorm_kernel<<<BT, 256, 0, stream>>>(x, norm1_w + l * D, h);
        gemm_kernel<1><<<dim3(3 * D / BN, BT / BM), 256, 0, stream>>>(
            h, qkv_w + (size_t)l * 3 * D * D, qkv, BT, 3 * D, D);
        attn_kernel<<<dim3(TT / 4, BB * NH), 256, 0, stream>>>(qkv, o);
        gemm_kernel<2><<<dim3(D / BN, BT / BM), 256, 0, stream>>>(
            o, proj_w + (size_t)l * D * D, x, BT, D, D);
        rmsnorm_kernel<<<BT, 256, 0, stream>>>(x, norm2_w + l * D, h);
        gemm_kernel<0><<<dim3(FF / BN, BT / BM), 256, 0, stream>>>(
            h, gate_w + (size_t)l * FF * D, g, BT, FF, D);
        gemm_kernel<0><<<dim3(FF / BN, BT / BM), 256, 0, stream>>>(
            h, up_w + (size_t)l * FF * D, u, BT, FF, D);
        silu_mul_kernel<<<(BT * FF) / 256, 256, 0, stream>>>(g, u, BT * FF);
        gemm_kernel<2><<<dim3(D / BN, BT / BM), 256, 0, stream>>>(
            g, down_w + (size_t)l * D * FF, x, BT, D, FF);
    }

    final_norm_kernel<<<2, 256, 0, stream>>>(x, normf_w, last);
    heads_kernel<<<(NS * NV * 64) / 256, 256, 0, stream>>>(last, heads_w, out);
}

// Round 2
// 4503.794 us; speedup vs baseline: 5.6590x; 5.6590x over previous
//
#include <hip/hip_runtime.h>
#include <hip/hip_bf16.h>

// Problem constants
#define LAYERS 12
#define NH     12
#define D      768
#define DH     64
#define FF     3072
#define NS     8
#define NV     1024
#define BB     2
#define TT     1024
#define BT     (BB*TT)          // 2048 token rows

typedef __attribute__((ext_vector_type(8))) short  short8;   // 8 bf16 (4 VGPRs)
typedef __attribute__((ext_vector_type(8))) unsigned short ushort8;
typedef __attribute__((ext_vector_type(4))) float  floatx4;  // MFMA C/D

// ---------------------------------------------------------------- utilities
__device__ __forceinline__ float wave_sum(float v) {
    v += __shfl_xor(v, 1);  v += __shfl_xor(v, 2);  v += __shfl_xor(v, 4);
    v += __shfl_xor(v, 8);  v += __shfl_xor(v, 16); v += __shfl_xor(v, 32);
    return v;
}
__device__ __forceinline__ unsigned short f2bf(float f) {
    unsigned int u = __builtin_bit_cast(unsigned int, f);
    u += 0x7fffu + ((u >> 16) & 1u);          // RNE
    return (unsigned short)(u >> 16);
}

// ---------------------------------------------------------------- embedding (fp32 x)
__global__ __launch_bounds__(256) void embed_kernel(
    const int* __restrict__ prev_tokens, const int* __restrict__ positions,
    const float* __restrict__ intent, const float* __restrict__ rvq,
    const float* __restrict__ pos_emb, float* __restrict__ x) {
    const int row = blockIdx.x;
    const int b   = row >> 10;
    __shared__ int toks[NS];
    __shared__ int p;
    if (threadIdx.x < NS) toks[threadIdx.x] = prev_tokens[row * NS + threadIdx.x];
    if (threadIdx.x == NS) p = positions[row];
    __syncthreads();
    for (int d = threadIdx.x; d < D; d += 256) {
        float acc = intent[b * D + d] + pos_emb[p * D + d];
        #pragma unroll
        for (int s = 0; s < NS; ++s)
            acc += rvq[((size_t)(s * NV + toks[s])) * D + d];
        x[(size_t)row * D + d] = acc;
    }
}

// ---------------------------------------------------------------- rmsnorm -> bf16
__global__ __launch_bounds__(256) void rmsnorm_kernel(
    const float* __restrict__ x, const float* __restrict__ w, unsigned short* __restrict__ h) {
    const int row = blockIdx.x;
    const float* xr = x + (size_t)row * D;
    float ss = 0.f;
    for (int d = threadIdx.x; d < D; d += 256) { float v = xr[d]; ss += v * v; }
    const int wave = threadIdx.x >> 6, lane = threadIdx.x & 63;
    __shared__ float red[4];
    float s = wave_sum(ss);
    if (lane == 0) red[wave] = s;
    __syncthreads();
    float tot = red[0] + red[1] + red[2] + red[3];
    float inv = rsqrtf(tot * (1.0f / D) + 1e-6f);
    for (int d = threadIdx.x; d < D; d += 256)
        h[(size_t)row * D + d] = f2bf(xr[d] * inv * w[d]);
}

// ---------------------------------------------------------------- bf16 MFMA GEMM
// C(MxN) = A(MxK)[bf16] @ W(NxK)^T[fp32, cvt in staging]
// MODE 0: fp32 store   MODE 1: bf16 qkv scatter [3][B,H,T,DH] (q scaled 0.125)
// MODE 2: fp32 residual add
#define GBM 128
#define GBN 128
#define GBK 32
#define APITCH 40   // bf16 units per LDS row (80B, 16B-aligned, breaks pow2 stride)
template <int MODE>
__global__ __launch_bounds__(256) void gemm_bf16(
    const unsigned short* __restrict__ A, const float* __restrict__ W,
    void* __restrict__ Cv, int M, int N, int K) {
    __shared__ unsigned short As[GBM * APITCH];
    __shared__ unsigned short Ws[GBN * APITCH];
    const int tid  = threadIdx.x;
    const int row0 = blockIdx.y * GBM;
    const int col0 = blockIdx.x * GBN;
    const int srow  = tid >> 1;       // 0..127
    const int shalf = tid & 1;        // 16 bf16 each half
    const int wv   = tid >> 6;
    const int lane = tid & 63;
    const int l15  = lane & 15;
    const int quad = lane >> 4;
    const int wave_m = (wv & 1) * 64;
    const int wave_n = (wv >> 1) * 64;

    floatx4 acc[4][4];
    #pragma unroll
    for (int i = 0; i < 4; ++i)
        #pragma unroll
        for (int j = 0; j < 4; ++j) acc[i][j] = (floatx4){0.f, 0.f, 0.f, 0.f};

    for (int k0 = 0; k0 < K; k0 += GBK) {
        // stage A (bf16 source): 16 bf16 per thread
        const unsigned short* ag = A + (size_t)(row0 + srow) * K + k0 + shalf * 16;
        ushort8 a0 = *(const ushort8*)(ag);
        ushort8 a1 = *(const ushort8*)(ag + 8);
        // stage W (fp32 source -> bf16): 16 floats per thread
        const float* wg = W + (size_t)(col0 + srow) * K + k0 + shalf * 16;
        float4 w0 = *(const float4*)(wg);
        float4 w1 = *(const float4*)(wg + 4);
        float4 w2 = *(const float4*)(wg + 8);
        float4 w3 = *(const float4*)(wg + 12);
        ushort8 wb0, wb1;
        wb0[0]=f2bf(w0.x); wb0[1]=f2bf(w0.y); wb0[2]=f2bf(w0.z); wb0[3]=f2bf(w0.w);
        wb0[4]=f2bf(w1.x); wb0[5]=f2bf(w1.y); wb0[6]=f2bf(w1.z); wb0[7]=f2bf(w1.w);
        wb1[0]=f2bf(w2.x); wb1[1]=f2bf(w2.y); wb1[2]=f2bf(w2.z); wb1[3]=f2bf(w2.w);
        wb1[4]=f2bf(w3.x); wb1[5]=f2bf(w3.y); wb1[6]=f2bf(w3.z); wb1[7]=f2bf(w3.w);
        __syncthreads();
        *(ushort8*)(&As[srow * APITCH + shalf * 16])     = a0;
        *(ushort8*)(&As[srow * APITCH + shalf * 16 + 8]) = a1;
        *(ushort8*)(&Ws[srow * APITCH + shalf * 16])     = wb0;
        *(ushort8*)(&Ws[srow * APITCH + shalf * 16 + 8]) = wb1;
        __syncthreads();
        short8 af[4], bf[4];
        #pragma unroll
        for (int i = 0; i < 4; ++i)
            af[i] = *(const short8*)(&As[(wave_m + i * 16 + l15) * APITCH + quad * 8]);
        #pragma unroll
        for (int j = 0; j < 4; ++j)
            bf[j] = *(const short8*)(&Ws[(wave_n + j * 16 + l15) * APITCH + quad * 8]);
        #pragma unroll
        for (int i = 0; i < 4; ++i)
            #pragma unroll
            for (int j = 0; j < 4; ++j)
                acc[i][j] = __builtin_amdgcn_mfma_f32_16x16x32_bf16(af[i], bf[j], acc[i][j], 0, 0, 0);
    }

    #pragma unroll
    for (int i = 0; i < 4; ++i) {
        #pragma unroll
        for (int j = 0; j < 4; ++j) {
            const int n = col0 + wave_n + j * 16 + l15;
            #pragma unroll
            for (int r = 0; r < 4; ++r) {
                const int m = row0 + wave_m + i * 16 + quad * 4 + r;
                const float v = acc[i][j][r];
                if (MODE == 0) {
                    ((float*)Cv)[(size_t)m * N + n] = v;
                } else if (MODE == 2) {
                    ((float*)Cv)[(size_t)m * N + n] += v;
                } else {
                    const int wsel = n / D;
                    const int rr = n - wsel * D;
                    const int hh = rr >> 6, dd = rr & 63;
                    const int b = m >> 10, t = m & 1023;
                    ((unsigned short*)Cv)[(size_t)wsel * (BT * D) +
                        (((size_t)(b * NH + hh)) * TT + t) * DH + dd] =
                        f2bf(wsel == 0 ? v * 0.125f : v);
                }
            }
        }
    }
}

// ---------------------------------------------------------------- MFMA flash attention
// qkv bf16 [3][B,H,T,DH]; grid (T/64, B*H); 4 waves, each owns 16 q rows.
#define KP 72   // LDS row pitch in bf16 (144B, 16B-aligned)
__global__ __launch_bounds__(256) void attn_mfma(
    const unsigned short* __restrict__ qkv, unsigned short* __restrict__ obf) {
    const int bh = blockIdx.y;
    const int b = bh / NH, h = bh - b * NH;
    const int qt = blockIdx.x;
    const int q0 = qt * 64;
    const int tid = threadIdx.x;
    const int wv = tid >> 6, lane = tid & 63;
    const int l15 = lane & 15, quad = lane >> 4;

    const unsigned short* Q = qkv + (size_t)bh * TT * DH;
    const unsigned short* K = qkv + (size_t)BT * D + (size_t)bh * TT * DH;
    const unsigned short* V = qkv + 2 * (size_t)BT * D + (size_t)bh * TT * DH;

    __shared__ unsigned short Ks[64 * KP];
    __shared__ unsigned short Vts[64 * KP];
    __shared__ unsigned short Pa[64 * KP];

    // Q A-fragments (q rows wv*16 + l15), k = dh
    short8 qf[2];
    #pragma unroll
    for (int c = 0; c < 2; ++c)
        qf[c] = *(const short8*)(Q + (size_t)(q0 + wv * 16 + l15) * DH + c * 32 + quad * 8);

    floatx4 o_acc[4];
    #pragma unroll
    for (int j = 0; j < 4; ++j) o_acc[j] = (floatx4){0.f, 0.f, 0.f, 0.f};
    float m_run[4] = {-INFINITY, -INFINITY, -INFINITY, -INFINITY};
    float l_run[4] = {0.f, 0.f, 0.f, 0.f};

    for (int kt = 0; kt <= qt; ++kt) {
        __syncthreads();
        {   // stage K tile (as-is) : thread -> (row, quarter of 16 bf16)
            const int krow = tid >> 2, kq = tid & 3;
            const unsigned short* kg = K + (size_t)(kt * 64 + krow) * DH + kq * 16;
            ushort8 k0v = *(const ushort8*)(kg);
            ushort8 k1v = *(const ushort8*)(kg + 8);
            *(ushort8*)(&Ks[krow * KP + kq * 16])     = k0v;
            *(ushort8*)(&Ks[krow * KP + kq * 16 + 8]) = k1v;
            // stage V transposed: thread -> (k pair, dh chunk of 8)
            const int kp = tid & 31, chunk = tid >> 5;
            const unsigned short* vg = V + (size_t)(kt * 64 + 2 * kp) * DH + chunk * 8;
            ushort8 v0 = *(const ushort8*)(vg);
            ushort8 v1 = *(const ushort8*)(vg + DH);
            #pragma unroll
            for (int j = 0; j < 8; ++j) {
                unsigned int pk = (unsigned int)v0[j] | ((unsigned int)v1[j] << 16);
                *(unsigned int*)(&Vts[(chunk * 8 + j) * KP + 2 * kp]) = pk;
            }
        }
        __syncthreads();

        // QK^T: S[q][k] ; n-tiles j over k
        floatx4 s[4];
        #pragma unroll
        for (int j = 0; j < 4; ++j) {
            short8 kb0 = *(const short8*)(&Ks[(j * 16 + l15) * KP + quad * 8]);
            short8 kb1 = *(const short8*)(&Ks[(j * 16 + l15) * KP + 32 + quad * 8]);
            floatx4 z = (floatx4){0.f, 0.f, 0.f, 0.f};
            z = __builtin_amdgcn_mfma_f32_16x16x32_bf16(qf[0], kb0, z, 0, 0, 0);
            s[j] = __builtin_amdgcn_mfma_f32_16x16x32_bf16(qf[1], kb1, z, 0, 0, 0);
        }
        // causal mask (diagonal tile only)
        if (kt == qt) {
            #pragma unroll
            for (int j = 0; j < 4; ++j) {
                const int k_rel = j * 16 + l15;
                #pragma unroll
                for (int r = 0; r < 4; ++r) {
                    const int q_rel = wv * 16 + quad * 4 + r;
                    if (k_rel > q_rel) s[j][r] = -INFINITY;
                }
            }
        }
        // online softmax per q row (rows live on lane bits 0..3)
        float p_sum[4];
        #pragma unroll
        for (int r = 0; r < 4; ++r) {
            float mt = fmaxf(fmaxf(s[0][r], s[1][r]), fmaxf(s[2][r], s[3][r]));
            mt = fmaxf(mt, __shfl_xor(mt, 1));
            mt = fmaxf(mt, __shfl_xor(mt, 2));
            mt = fmaxf(mt, __shfl_xor(mt, 4));
            mt = fmaxf(mt, __shfl_xor(mt, 8));
            const float m_new = fmaxf(m_run[r], mt);
            const float alpha = __expf(m_run[r] - m_new);
            float rs = 0.f;
            #pragma unroll
            for (int j = 0; j < 4; ++j) {
                const float p = __expf(s[j][r] - m_new);
                s[j][r] = p;
                rs += p;
            }
            rs += __shfl_xor(rs, 1);
            rs += __shfl_xor(rs, 2);
            rs += __shfl_xor(rs, 4);
            rs += __shfl_xor(rs, 8);
            l_run[r] = l_run[r] * alpha + rs;
            m_run[r] = m_new;
            #pragma unroll
            for (int j = 0; j < 4; ++j) o_acc[j][r] *= alpha;
        }
        // P -> LDS (A-layout rows), same-wave region: no barrier needed
        #pragma unroll
        for (int j = 0; j < 4; ++j)
            #pragma unroll
            for (int r = 0; r < 4; ++r)
                Pa[(wv * 16 + quad * 4 + r) * KP + j * 16 + l15] = f2bf(s[j][r]);
        // PV: A = P fragments, B = Vt fragments
        short8 pa0 = *(const short8*)(&Pa[(wv * 16 + l15) * KP + quad * 8]);
        short8 pa1 = *(const short8*)(&Pa[(wv * 16 + l15) * KP + 32 + quad * 8]);
        #pragma unroll
        for (int j = 0; j < 4; ++j) {
            short8 vb0 = *(const short8*)(&Vts[(j * 16 + l15) * KP + quad * 8]);
            short8 vb1 = *(const short8*)(&Vts[(j * 16 + l15) * KP + 32 + quad * 8]);
            o_acc[j] = __builtin_amdgcn_mfma_f32_16x16x32_bf16(pa0, vb0, o_acc[j], 0, 0, 0);
            o_acc[j] = __builtin_amdgcn_mfma_f32_16x16x32_bf16(pa1, vb1, o_acc[j], 0, 0, 0);
        }
    }
    // write O (bf16) as (B,T,H*DH)
    #pragma unroll
    for (int j = 0; j < 4; ++j) {
        #pragma unroll
        for (int r = 0; r < 4; ++r) {
            const int t = q0 + wv * 16 + quad * 4 + r;
            const int ch = h * DH + j * 16 + l15;
            obf[((size_t)(b * TT + t)) * D + ch] = f2bf(o_acc[j][r] / l_run[r]);
        }
    }
}

// ---------------------------------------------------------------- silu(g)*u -> bf16
__global__ __launch_bounds__(256) void silu_mul_kernel(
    const float* __restrict__ g, const float* __restrict__ u,
    unsigned short* __restrict__ gb, int n4) {
    const int i = blockIdx.x * 256 + threadIdx.x;
    if (i < n4) {
        float4 gv = *(const float4*)(g + (size_t)i * 4);
        float4 uv = *(const float4*)(u + (size_t)i * 4);
        ushort4 o;
        o.x = f2bf(gv.x / (1.f + __expf(-gv.x)) * uv.x);
        o.y = f2bf(gv.y / (1.f + __expf(-gv.y)) * uv.y);
        o.z = f2bf(gv.z / (1.f + __expf(-gv.z)) * uv.z);
        o.w = f2bf(gv.w / (1.f + __expf(-gv.w)) * uv.w);
        *(ushort4*)(gb + (size_t)i * 4) = o;
    }
}

// ---------------------------------------------------------------- final norm (last tokens)
__global__ __launch_bounds__(256) void final_norm_kernel(
    const float* __restrict__ x, const float* __restrict__ w, float* __restrict__ last) {
    const int b = blockIdx.x;
    const float* xr = x + ((size_t)(b * TT + (TT - 1))) * D;
    float ss = 0.f;
    for (int d = threadIdx.x; d < D; d += 256) { float v = xr[d]; ss += v * v; }
    const int wave = threadIdx.x >> 6, lane = threadIdx.x & 63;
    __shared__ float red[4];
    float s = wave_sum(ss);
    if (lane == 0) red[wave] = s;
    __syncthreads();
    float tot = red[0] + red[1] + red[2] + red[3];
    float inv = rsqrtf(tot * (1.0f / D) + 1e-6f);
    for (int d = threadIdx.x; d < D; d += 256)
        last[(size_t)b * D + d] = xr[d] * inv * w[d];
}

// ---------------------------------------------------------------- heads
__global__ __launch_bounds__(256) void heads_kernel(
    const float* __restrict__ last, const float* __restrict__ hw, float* __restrict__ out) {
    const int gw = (blockIdx.x * 256 + threadIdx.x) >> 6;
    const int lane = threadIdx.x & 63;
    const int s = gw >> 10, v = gw & 1023;
    const float* w = hw + (size_t)gw * D;
    float a0 = 0.f, a1 = 0.f;
    for (int d = lane; d < D; d += 64) {
        const float ww = w[d];
        a0 = fmaf(ww, last[d], a0);
        a1 = fmaf(ww, last[D + d], a1);
    }
    a0 = wave_sum(a0);
    a1 = wave_sum(a1);
    if (lane == 0) {
        out[((size_t)s * BB + 0) * NV + v] = a0;
        out[((size_t)s * BB + 1) * NV + v] = a1;
    }
}

// ---------------------------------------------------------------- launcher
extern "C" void kernel_launch(void* const* d_in, const int* in_sizes, int n_in,
                              void* d_out, int out_size, void* d_ws, size_t ws_size,
                              hipStream_t stream) {
    const int*   prev_tokens = (const int*)  d_in[0];
    const int*   positions   = (const int*)  d_in[1];
    const float* intent      = (const float*)d_in[2];
    const float* rvq         = (const float*)d_in[3];
    const float* pos_emb     = (const float*)d_in[4];
    const float* norm1_w     = (const float*)d_in[5];
    const float* norm2_w     = (const float*)d_in[6];
    const float* qkv_w       = (const float*)d_in[7];
    const float* proj_w      = (const float*)d_in[8];
    const float* gate_w      = (const float*)d_in[9];
    const float* up_w        = (const float*)d_in[10];
    const float* down_w      = (const float*)d_in[11];
    const float* normf_w     = (const float*)d_in[12];
    const float* heads_w     = (const float*)d_in[13];
    float* out = (float*)d_out;

    char* base = (char*)d_ws;
    float* x   = (float*)base;                       base += (size_t)BT * D * 4;
    float* g   = (float*)base;                       base += (size_t)BT * FF * 4;
    float* u   = (float*)base;                       base += (size_t)BT * FF * 4;
    float* last= (float*)base;                       base += 2 * D * 4;
    unsigned short* hbf    = (unsigned short*)base;  base += (size_t)BT * D * 2;
    unsigned short* qkvbf  = (unsigned short*)base;  base += (size_t)3 * BT * D * 2;
    unsigned short* obf    = (unsigned short*)base;  base += (size_t)BT * D * 2;
    unsigned short* gbf    = (unsigned short*)base;  base += (size_t)BT * FF * 2;

    embed_kernel<<<BT, 256, 0, stream>>>(prev_tokens, positions, intent, rvq, pos_emb, x);

    for (int l = 0; l < LAYERS; ++l) {
        rmsnorm_kernel<<<BT, 256, 0, stream>>>(x, norm1_w + l * D, hbf);
        gemm_bf16<1><<<dim3(3 * D / GBN, BT / GBM), 256, 0, stream>>>(
            hbf, qkv_w + (size_t)l * 3 * D * D, qkvbf, BT, 3 * D, D);
        attn_mfma<<<dim3(TT / 64, BB * NH), 256, 0, stream>>>(qkvbf, obf);
        gemm_bf16<2><<<dim3(D / GBN, BT / GBM), 256, 0, stream>>>(
            obf, proj_w + (size_t)l * D * D, x, BT, D, D);
        rmsnorm_kernel<<<BT, 256, 0, stream>>>(x, norm2_w + l * D, hbf);
        gemm_bf16<0><<<dim3(FF / GBN, BT / GBM), 256, 0, stream>>>(
            hbf, gate_w + (size_t)l * FF * D, g, BT, FF, D);
        gemm_bf16<0><<<dim3(FF / GBN, BT / GBM), 256, 0, stream>>>(
            hbf, up_w + (size_t)l * FF * D, u, BT, FF, D);
        silu_mul_kernel<<<(BT * FF / 4 + 255) / 256, 256, 0, stream>>>(g, u, gbf, BT * FF / 4);
        gemm_bf16<2><<<dim3(D / GBN, BT / GBM), 256, 0, stream>>>(
            gbf, down_w + (size_t)l * D * FF, x, BT, D, FF);
    }

    final_norm_kernel<<<2, 256, 0, stream>>>(x, normf_w, last);
    heads_kernel<<<(NS * NV * 64) / 256, 256, 0, stream>>>(last, heads_w, out);
}

// Round 3
// 2520.742 us; speedup vs baseline: 10.1109x; 1.7867x over previous
//
#include <hip/hip_runtime.h>
#include <hip/hip_bf16.h>

// Problem constants
#define LAYERS 12
#define NH     12
#define D      768
#define DH     64
#define FF     3072
#define NS     8
#define NV     1024
#define BB     2
#define TT     1024
#define BT     (BB*TT)          // 2048 token rows

typedef __attribute__((ext_vector_type(8))) short  short8;   // 8 bf16 (4 VGPRs)
typedef __attribute__((ext_vector_type(8))) unsigned short ushort8;
typedef __attribute__((ext_vector_type(4))) float  floatx4;  // MFMA C/D

#define PITCH 72   // bf16 units per LDS row (144 B): conflict-free for b128 frag reads

// ---------------------------------------------------------------- utilities
__device__ __forceinline__ float wave_sum(float v) {
    v += __shfl_xor(v, 1);  v += __shfl_xor(v, 2);  v += __shfl_xor(v, 4);
    v += __shfl_xor(v, 8);  v += __shfl_xor(v, 16); v += __shfl_xor(v, 32);
    return v;
}
__device__ __forceinline__ unsigned short f2bf(float f) {
    unsigned int u = __builtin_bit_cast(unsigned int, f);
    u += 0x7fffu + ((u >> 16) & 1u);          // RNE
    return (unsigned short)(u >> 16);
}
__device__ __forceinline__ ushort8 pack8(float4 f0, float4 f1) {
    ushort8 r;
    r[0]=f2bf(f0.x); r[1]=f2bf(f0.y); r[2]=f2bf(f0.z); r[3]=f2bf(f0.w);
    r[4]=f2bf(f1.x); r[5]=f2bf(f1.y); r[6]=f2bf(f1.z); r[7]=f2bf(f1.w);
    return r;
}

// ---------------------------------------------------------------- embedding (fp32 x)
__global__ __launch_bounds__(256) void embed_kernel(
    const int* __restrict__ prev_tokens, const int* __restrict__ positions,
    const float* __restrict__ intent, const float* __restrict__ rvq,
    const float* __restrict__ pos_emb, float* __restrict__ x) {
    const int row = blockIdx.x;
    const int b   = row >> 10;
    __shared__ int toks[NS];
    __shared__ int p;
    if (threadIdx.x < NS) toks[threadIdx.x] = prev_tokens[row * NS + threadIdx.x];
    if (threadIdx.x == NS) p = positions[row];
    __syncthreads();
    for (int d = threadIdx.x; d < D; d += 256) {
        float acc = intent[b * D + d] + pos_emb[p * D + d];
        #pragma unroll
        for (int s = 0; s < NS; ++s)
            acc += rvq[((size_t)(s * NV + toks[s])) * D + d];
        x[(size_t)row * D + d] = acc;
    }
}

// ---------------------------------------------------------------- rmsnorm -> bf16
__global__ __launch_bounds__(256) void rmsnorm_kernel(
    const float* __restrict__ x, const float* __restrict__ w, unsigned short* __restrict__ h) {
    const int row = blockIdx.x;
    const float* xr = x + (size_t)row * D;
    float ss = 0.f;
    for (int d = threadIdx.x; d < D; d += 256) { float v = xr[d]; ss += v * v; }
    const int wave = threadIdx.x >> 6, lane = threadIdx.x & 63;
    __shared__ float red[4];
    float s = wave_sum(ss);
    if (lane == 0) red[wave] = s;
    __syncthreads();
    float tot = red[0] + red[1] + red[2] + red[3];
    float inv = rsqrtf(tot * (1.0f / D) + 1e-6f);
    for (int d = threadIdx.x; d < D; d += 256)
        h[(size_t)row * D + d] = f2bf(xr[d] * inv * w[d]);
}

// ---------------------------------------------------------------- bf16 MFMA GEMM, 128x128, BK=64
// C(MxN) = A(MxK)[bf16] @ W(NxK)^T[fp32 -> bf16 in staging]
// MODE 1: bf16 qkv scatter [3][B,H,T,DH] (q scaled 0.125)
// MODE 2: fp32 +=  (single split only)
// MODE 3: fp32 atomicAdd (split-K)
template <int MODE, int SPLITK>
__global__ __launch_bounds__(256) void gemm128(
    const unsigned short* __restrict__ A, const float* __restrict__ W,
    void* __restrict__ Cv, int M, int N, int K) {
    __shared__ unsigned short As[128 * PITCH];
    __shared__ unsigned short Ws[128 * PITCH];
    const int tid  = threadIdx.x;
    const int row0 = blockIdx.y * 128;
    const int col0 = blockIdx.x * 128;
    const int kchunk = K / SPLITK;
    const int kbeg = blockIdx.z * kchunk;
    const int kend = kbeg + kchunk;
    const int wv = tid >> 6, lane = tid & 63;
    const int l15 = lane & 15, quad = lane >> 4;
    const int wm = (wv & 1) * 64, wn = (wv >> 1) * 64;

    floatx4 acc[4][4];
    #pragma unroll
    for (int i = 0; i < 4; ++i)
        #pragma unroll
        for (int j = 0; j < 4; ++j) acc[i][j] = (floatx4){0.f, 0.f, 0.f, 0.f};

    for (int k0 = kbeg; k0 < kend; k0 += 64) {
        // global loads: A 16-B chunks (1024 chunks), W 8-float pairs (1024 pairs)
        ushort8 a_ld[4], w_ld[4];
        #pragma unroll
        for (int q = 0; q < 4; ++q) {
            const int ch = tid + 256 * q;        // 0..1023
            const int r = ch >> 3, sl = ch & 7;
            a_ld[q] = *(const ushort8*)(A + (size_t)(row0 + r) * K + k0 + sl * 8);
            const float* wp = W + (size_t)(col0 + r) * K + k0 + sl * 8;
            float4 f0 = *(const float4*)(wp);
            float4 f1 = *(const float4*)(wp + 4);
            w_ld[q] = pack8(f0, f1);
        }
        __syncthreads();
        #pragma unroll
        for (int q = 0; q < 4; ++q) {
            const int ch = tid + 256 * q;
            const int r = ch >> 3, sl = ch & 7;
            *(ushort8*)(&As[r * PITCH + sl * 8]) = a_ld[q];
            *(ushort8*)(&Ws[r * PITCH + sl * 8]) = w_ld[q];
        }
        __syncthreads();
        #pragma unroll
        for (int ks = 0; ks < 2; ++ks) {
            short8 af[4], bf[4];
            #pragma unroll
            for (int i = 0; i < 4; ++i)
                af[i] = *(const short8*)(&As[(wm + i * 16 + l15) * PITCH + ks * 32 + quad * 8]);
            #pragma unroll
            for (int j = 0; j < 4; ++j)
                bf[j] = *(const short8*)(&Ws[(wn + j * 16 + l15) * PITCH + ks * 32 + quad * 8]);
            #pragma unroll
            for (int i = 0; i < 4; ++i)
                #pragma unroll
                for (int j = 0; j < 4; ++j)
                    acc[i][j] = __builtin_amdgcn_mfma_f32_16x16x32_bf16(af[i], bf[j], acc[i][j], 0, 0, 0);
        }
    }

    #pragma unroll
    for (int i = 0; i < 4; ++i) {
        #pragma unroll
        for (int j = 0; j < 4; ++j) {
            const int n = col0 + wn + j * 16 + l15;
            #pragma unroll
            for (int r = 0; r < 4; ++r) {
                const int m = row0 + wm + i * 16 + quad * 4 + r;
                const float v = acc[i][j][r];
                if (MODE == 2) {
                    ((float*)Cv)[(size_t)m * N + n] += v;
                } else if (MODE == 3) {
                    atomicAdd(&((float*)Cv)[(size_t)m * N + n], v);
                } else { // MODE 1: qkv scatter
                    const int wsel = n / D;
                    const int rr = n - wsel * D;
                    const int hh = rr >> 6, dd = rr & 63;
                    const int b = m >> 10, t = m & 1023;
                    ((unsigned short*)Cv)[(size_t)wsel * (BT * D) +
                        (((size_t)(b * NH + hh)) * TT + t) * DH + dd] =
                        f2bf(wsel == 0 ? v * 0.125f : v);
                }
            }
        }
    }
}

// ---------------------------------------------------------------- fused gate/up/silu GEMM
// tile: 128 M x 64 N (for BOTH gate and up), BK=64; waves 2x2, each 64x32 per output.
// gbf[m, n] = silu(gate) * up, bf16.
__global__ __launch_bounds__(256) void gateup128(
    const unsigned short* __restrict__ A, const float* __restrict__ Wg,
    const float* __restrict__ Wu, unsigned short* __restrict__ gbf, int K) {
    __shared__ unsigned short As[128 * PITCH];
    __shared__ unsigned short Gs[64 * PITCH];
    __shared__ unsigned short Us[64 * PITCH];
    const int tid  = threadIdx.x;
    const int row0 = blockIdx.y * 128;
    const int col0 = blockIdx.x * 64;
    const int wv = tid >> 6, lane = tid & 63;
    const int l15 = lane & 15, quad = lane >> 4;
    const int wm = (wv & 1) * 64, wn = (wv >> 1) * 32;

    floatx4 ag[4][2], au[4][2];
    #pragma unroll
    for (int i = 0; i < 4; ++i)
        #pragma unroll
        for (int j = 0; j < 2; ++j) {
            ag[i][j] = (floatx4){0.f, 0.f, 0.f, 0.f};
            au[i][j] = (floatx4){0.f, 0.f, 0.f, 0.f};
        }

    for (int k0 = 0; k0 < K; k0 += 64) {
        ushort8 a_ld[4], w_ld[4];
        #pragma unroll
        for (int q = 0; q < 4; ++q) {
            const int ch = tid + 256 * q;
            const int r = ch >> 3, sl = ch & 7;
            a_ld[q] = *(const ushort8*)(A + (size_t)(row0 + r) * K + k0 + sl * 8);
            // W pairs: q<2 -> gate rows 0..63, q>=2 -> up rows 0..63
            const int p  = (ch & 511);
            const int wr = p >> 3, wsl = p & 7;
            const float* wp = (q < 2 ? Wg : Wu) + (size_t)(col0 + wr) * K + k0 + wsl * 8;
            float4 f0 = *(const float4*)(wp);
            float4 f1 = *(const float4*)(wp + 4);
            w_ld[q] = pack8(f0, f1);
        }
        __syncthreads();
        #pragma unroll
        for (int q = 0; q < 4; ++q) {
            const int ch = tid + 256 * q;
            const int r = ch >> 3, sl = ch & 7;
            *(ushort8*)(&As[r * PITCH + sl * 8]) = a_ld[q];
            const int p  = (ch & 511);
            const int wr = p >> 3, wsl = p & 7;
            unsigned short* dst = (q < 2 ? Gs : Us);
            *(ushort8*)(&dst[wr * PITCH + wsl * 8]) = w_ld[q];
        }
        __syncthreads();
        #pragma unroll
        for (int ks = 0; ks < 2; ++ks) {
            short8 af[4], bg[2], bu[2];
            #pragma unroll
            for (int i = 0; i < 4; ++i)
                af[i] = *(const short8*)(&As[(wm + i * 16 + l15) * PITCH + ks * 32 + quad * 8]);
            #pragma unroll
            for (int j = 0; j < 2; ++j) {
                bg[j] = *(const short8*)(&Gs[(wn + j * 16 + l15) * PITCH + ks * 32 + quad * 8]);
                bu[j] = *(const short8*)(&Us[(wn + j * 16 + l15) * PITCH + ks * 32 + quad * 8]);
            }
            #pragma unroll
            for (int i = 0; i < 4; ++i)
                #pragma unroll
                for (int j = 0; j < 2; ++j) {
                    ag[i][j] = __builtin_amdgcn_mfma_f32_16x16x32_bf16(af[i], bg[j], ag[i][j], 0, 0, 0);
                    au[i][j] = __builtin_amdgcn_mfma_f32_16x16x32_bf16(af[i], bu[j], au[i][j], 0, 0, 0);
                }
        }
    }

    #pragma unroll
    for (int i = 0; i < 4; ++i) {
        #pragma unroll
        for (int j = 0; j < 2; ++j) {
            const int n = col0 + wn + j * 16 + l15;
            #pragma unroll
            for (int r = 0; r < 4; ++r) {
                const int m = row0 + wm + i * 16 + quad * 4 + r;
                const float gv = ag[i][j][r], uv = au[i][j][r];
                gbf[(size_t)m * FF + n] = f2bf(gv / (1.f + __expf(-gv)) * uv);
            }
        }
    }
}

// ---------------------------------------------------------------- MFMA flash attention
#define KP 72
__global__ __launch_bounds__(256) void attn_mfma(
    const unsigned short* __restrict__ qkv, unsigned short* __restrict__ obf) {
    const int bh = blockIdx.y;
    const int b = bh / NH, h = bh - b * NH;
    const int qt = blockIdx.x;
    const int q0 = qt * 64;
    const int tid = threadIdx.x;
    const int wv = tid >> 6, lane = tid & 63;
    const int l15 = lane & 15, quad = lane >> 4;

    const unsigned short* Q = qkv + (size_t)bh * TT * DH;
    const unsigned short* K = qkv + (size_t)BT * D + (size_t)bh * TT * DH;
    const unsigned short* V = qkv + 2 * (size_t)BT * D + (size_t)bh * TT * DH;

    __shared__ unsigned short Ks[64 * KP];
    __shared__ unsigned short Vts[64 * KP];
    __shared__ unsigned short Pa[64 * KP];

    short8 qf[2];
    #pragma unroll
    for (int c = 0; c < 2; ++c)
        qf[c] = *(const short8*)(Q + (size_t)(q0 + wv * 16 + l15) * DH + c * 32 + quad * 8);

    floatx4 o_acc[4];
    #pragma unroll
    for (int j = 0; j < 4; ++j) o_acc[j] = (floatx4){0.f, 0.f, 0.f, 0.f};
    float m_run[4] = {-INFINITY, -INFINITY, -INFINITY, -INFINITY};
    float l_run[4] = {0.f, 0.f, 0.f, 0.f};

    for (int kt = 0; kt <= qt; ++kt) {
        __syncthreads();
        {
            const int krow = tid >> 2, kq = tid & 3;
            const unsigned short* kg = K + (size_t)(kt * 64 + krow) * DH + kq * 16;
            ushort8 k0v = *(const ushort8*)(kg);
            ushort8 k1v = *(const ushort8*)(kg + 8);
            *(ushort8*)(&Ks[krow * KP + kq * 16])     = k0v;
            *(ushort8*)(&Ks[krow * KP + kq * 16 + 8]) = k1v;
            const int kp = tid & 31, chunk = tid >> 5;
            const unsigned short* vg = V + (size_t)(kt * 64 + 2 * kp) * DH + chunk * 8;
            ushort8 v0 = *(const ushort8*)(vg);
            ushort8 v1 = *(const ushort8*)(vg + DH);
            #pragma unroll
            for (int j = 0; j < 8; ++j) {
                unsigned int pk = (unsigned int)v0[j] | ((unsigned int)v1[j] << 16);
                *(unsigned int*)(&Vts[(chunk * 8 + j) * KP + 2 * kp]) = pk;
            }
        }
        __syncthreads();

        floatx4 s[4];
        #pragma unroll
        for (int j = 0; j < 4; ++j) {
            short8 kb0 = *(const short8*)(&Ks[(j * 16 + l15) * KP + quad * 8]);
            short8 kb1 = *(const short8*)(&Ks[(j * 16 + l15) * KP + 32 + quad * 8]);
            floatx4 z = (floatx4){0.f, 0.f, 0.f, 0.f};
            z = __builtin_amdgcn_mfma_f32_16x16x32_bf16(qf[0], kb0, z, 0, 0, 0);
            s[j] = __builtin_amdgcn_mfma_f32_16x16x32_bf16(qf[1], kb1, z, 0, 0, 0);
        }
        if (kt == qt) {
            #pragma unroll
            for (int j = 0; j < 4; ++j) {
                const int k_rel = j * 16 + l15;
                #pragma unroll
                for (int r = 0; r < 4; ++r) {
                    const int q_rel = wv * 16 + quad * 4 + r;
                    if (k_rel > q_rel) s[j][r] = -INFINITY;
                }
            }
        }
        #pragma unroll
        for (int r = 0; r < 4; ++r) {
            float mt = fmaxf(fmaxf(s[0][r], s[1][r]), fmaxf(s[2][r], s[3][r]));
            mt = fmaxf(mt, __shfl_xor(mt, 1));
            mt = fmaxf(mt, __shfl_xor(mt, 2));
            mt = fmaxf(mt, __shfl_xor(mt, 4));
            mt = fmaxf(mt, __shfl_xor(mt, 8));
            const float m_new = fmaxf(m_run[r], mt);
            const float alpha = __expf(m_run[r] - m_new);
            float rs = 0.f;
            #pragma unroll
            for (int j = 0; j < 4; ++j) {
                const float p = __expf(s[j][r] - m_new);
                s[j][r] = p;
                rs += p;
            }
            rs += __shfl_xor(rs, 1);
            rs += __shfl_xor(rs, 2);
            rs += __shfl_xor(rs, 4);
            rs += __shfl_xor(rs, 8);
            l_run[r] = l_run[r] * alpha + rs;
            m_run[r] = m_new;
            #pragma unroll
            for (int j = 0; j < 4; ++j) o_acc[j][r] *= alpha;
        }
        #pragma unroll
        for (int j = 0; j < 4; ++j)
            #pragma unroll
            for (int r = 0; r < 4; ++r)
                Pa[(wv * 16 + quad * 4 + r) * KP + j * 16 + l15] = f2bf(s[j][r]);
        short8 pa0 = *(const short8*)(&Pa[(wv * 16 + l15) * KP + quad * 8]);
        short8 pa1 = *(const short8*)(&Pa[(wv * 16 + l15) * KP + 32 + quad * 8]);
        #pragma unroll
        for (int j = 0; j < 4; ++j) {
            short8 vb0 = *(const short8*)(&Vts[(j * 16 + l15) * KP + quad * 8]);
            short8 vb1 = *(const short8*)(&Vts[(j * 16 + l15) * KP + 32 + quad * 8]);
            o_acc[j] = __builtin_amdgcn_mfma_f32_16x16x32_bf16(pa0, vb0, o_acc[j], 0, 0, 0);
            o_acc[j] = __builtin_amdgcn_mfma_f32_16x16x32_bf16(pa1, vb1, o_acc[j], 0, 0, 0);
        }
    }
    #pragma unroll
    for (int j = 0; j < 4; ++j) {
        #pragma unroll
        for (int r = 0; r < 4; ++r) {
            const int t = q0 + wv * 16 + quad * 4 + r;
            const int ch = h * DH + j * 16 + l15;
            obf[((size_t)(b * TT + t)) * D + ch] = f2bf(o_acc[j][r] / l_run[r]);
        }
    }
}

// ---------------------------------------------------------------- final norm (last tokens)
__global__ __launch_bounds__(256) void final_norm_kernel(
    const float* __restrict__ x, const float* __restrict__ w, float* __restrict__ last) {
    const int b = blockIdx.x;
    const float* xr = x + ((size_t)(b * TT + (TT - 1))) * D;
    float ss = 0.f;
    for (int d = threadIdx.x; d < D; d += 256) { float v = xr[d]; ss += v * v; }
    const int wave = threadIdx.x >> 6, lane = threadIdx.x & 63;
    __shared__ float red[4];
    float s = wave_sum(ss);
    if (lane == 0) red[wave] = s;
    __syncthreads();
    float tot = red[0] + red[1] + red[2] + red[3];
    float inv = rsqrtf(tot * (1.0f / D) + 1e-6f);
    for (int d = threadIdx.x; d < D; d += 256)
        last[(size_t)b * D + d] = xr[d] * inv * w[d];
}

// ---------------------------------------------------------------- heads
__global__ __launch_bounds__(256) void heads_kernel(
    const float* __restrict__ last, const float* __restrict__ hw, float* __restrict__ out) {
    const int gw = (blockIdx.x * 256 + threadIdx.x) >> 6;
    const int lane = threadIdx.x & 63;
    const int s = gw >> 10, v = gw & 1023;
    const float* w = hw + (size_t)gw * D;
    float a0 = 0.f, a1 = 0.f;
    for (int d = lane; d < D; d += 64) {
        const float ww = w[d];
        a0 = fmaf(ww, last[d], a0);
        a1 = fmaf(ww, last[D + d], a1);
    }
    a0 = wave_sum(a0);
    a1 = wave_sum(a1);
    if (lane == 0) {
        out[((size_t)s * BB + 0) * NV + v] = a0;
        out[((size_t)s * BB + 1) * NV + v] = a1;
    }
}

// ---------------------------------------------------------------- launcher
extern "C" void kernel_launch(void* const* d_in, const int* in_sizes, int n_in,
                              void* d_out, int out_size, void* d_ws, size_t ws_size,
                              hipStream_t stream) {
    const int*   prev_tokens = (const int*)  d_in[0];
    const int*   positions   = (const int*)  d_in[1];
    const float* intent      = (const float*)d_in[2];
    const float* rvq         = (const float*)d_in[3];
    const float* pos_emb     = (const float*)d_in[4];
    const float* norm1_w     = (const float*)d_in[5];
    const float* norm2_w     = (const float*)d_in[6];
    const float* qkv_w       = (const float*)d_in[7];
    const float* proj_w      = (const float*)d_in[8];
    const float* gate_w      = (const float*)d_in[9];
    const float* up_w        = (const float*)d_in[10];
    const float* down_w      = (const float*)d_in[11];
    const float* normf_w     = (const float*)d_in[12];
    const float* heads_w     = (const float*)d_in[13];
    float* out = (float*)d_out;

    char* base = (char*)d_ws;
    float* x   = (float*)base;                       base += (size_t)BT * D * 4;
    float* last= (float*)base;                       base += 2 * D * 4;
    unsigned short* hbf    = (unsigned short*)base;  base += (size_t)BT * D * 2;
    unsigned short* qkvbf  = (unsigned short*)base;  base += (size_t)3 * BT * D * 2;
    unsigned short* obf    = (unsigned short*)base;  base += (size_t)BT * D * 2;
    unsigned short* gbf    = (unsigned short*)base;  base += (size_t)BT * FF * 2;

    embed_kernel<<<BT, 256, 0, stream>>>(prev_tokens, positions, intent, rvq, pos_emb, x);

    for (int l = 0; l < LAYERS; ++l) {
        rmsnorm_kernel<<<BT, 256, 0, stream>>>(x, norm1_w + l * D, hbf);
        gemm128<1, 1><<<dim3(3 * D / 128, BT / 128, 1), 256, 0, stream>>>(
            hbf, qkv_w + (size_t)l * 3 * D * D, qkvbf, BT, 3 * D, D);
        attn_mfma<<<dim3(TT / 64, BB * NH), 256, 0, stream>>>(qkvbf, obf);
        gemm128<3, 2><<<dim3(D / 128, BT / 128, 2), 256, 0, stream>>>(
            obf, proj_w + (size_t)l * D * D, x, BT, D, D);
        rmsnorm_kernel<<<BT, 256, 0, stream>>>(x, norm2_w + l * D, hbf);
        gateup128<<<dim3(FF / 64, BT / 128), 256, 0, stream>>>(
            hbf, gate_w + (size_t)l * FF * D, up_w + (size_t)l * FF * D, gbf, D);
        gemm128<3, 4><<<dim3(D / 128, BT / 128, 4), 256, 0, stream>>>(
            gbf, down_w + (size_t)l * D * FF, x, BT, D, FF);
    }

    final_norm_kernel<<<2, 256, 0, stream>>>(x, normf_w, last);
    heads_kernel<<<(NS * NV * 64) / 256, 256, 0, stream>>>(last, heads_w, out);
}

// Round 4
// 2217.662 us; speedup vs baseline: 11.4927x; 1.1367x over previous
//
#include <hip/hip_runtime.h>
#include <hip/hip_bf16.h>

// Problem constants
#define LAYERS 12
#define NH     12
#define D      768
#define DH     64
#define FF     3072
#define NS     8
#define NV     1024
#define BB     2
#define TT     1024
#define BT     (BB*TT)          // 2048 token rows

typedef __attribute__((ext_vector_type(8))) short  short8;   // 8 bf16 (4 VGPRs)
typedef __attribute__((ext_vector_type(8))) unsigned short ushort8;
typedef __attribute__((ext_vector_type(4))) float  floatx4;  // MFMA C/D

// ---------------------------------------------------------------- utilities
__device__ __forceinline__ float wave_sum(float v) {
    v += __shfl_xor(v, 1);  v += __shfl_xor(v, 2);  v += __shfl_xor(v, 4);
    v += __shfl_xor(v, 8);  v += __shfl_xor(v, 16); v += __shfl_xor(v, 32);
    return v;
}
__device__ __forceinline__ unsigned short f2bf(float f) {
    unsigned int u = __builtin_bit_cast(unsigned int, f);
    u += 0x7fffu + ((u >> 16) & 1u);          // RNE
    return (unsigned short)(u >> 16);
}
__device__ __forceinline__ ushort8 pack8(float4 f0, float4 f1) {
    ushort8 r;
    r[0]=f2bf(f0.x); r[1]=f2bf(f0.y); r[2]=f2bf(f0.z); r[3]=f2bf(f0.w);
    r[4]=f2bf(f1.x); r[5]=f2bf(f1.y); r[6]=f2bf(f1.z); r[7]=f2bf(f1.w);
    return r;
}
// async global->LDS 16B DMA; dest = wave-uniform base + lane*16
__device__ __forceinline__ void gl2lds16(const void* g, void* l) {
    __builtin_amdgcn_global_load_lds(
        (const __attribute__((address_space(1))) unsigned int*)g,
        (__attribute__((address_space(3))) unsigned int*)l, 16, 0, 0);
}

// ---------------------------------------------------------------- fp32 -> bf16 weight convert
__global__ __launch_bounds__(256) void cvt_bf16_kernel(
    const float* __restrict__ w, unsigned short* __restrict__ o, int n8) {
    const int i = blockIdx.x * 256 + threadIdx.x;
    if (i < n8) {
        const float* p = w + (size_t)i * 8;
        float4 f0 = *(const float4*)p;
        float4 f1 = *(const float4*)(p + 4);
        *(ushort8*)(o + (size_t)i * 8) = pack8(f0, f1);
    }
}

// ---------------------------------------------------------------- embedding (fp32 x)
__global__ __launch_bounds__(256) void embed_kernel(
    const int* __restrict__ prev_tokens, const int* __restrict__ positions,
    const float* __restrict__ intent, const float* __restrict__ rvq,
    const float* __restrict__ pos_emb, float* __restrict__ x) {
    const int row = blockIdx.x;
    const int b   = row >> 10;
    __shared__ int toks[NS];
    __shared__ int p;
    if (threadIdx.x < NS) toks[threadIdx.x] = prev_tokens[row * NS + threadIdx.x];
    if (threadIdx.x == NS) p = positions[row];
    __syncthreads();
    for (int d = threadIdx.x; d < D; d += 256) {
        float acc = intent[b * D + d] + pos_emb[p * D + d];
        #pragma unroll
        for (int s = 0; s < NS; ++s)
            acc += rvq[((size_t)(s * NV + toks[s])) * D + d];
        x[(size_t)row * D + d] = acc;
    }
}

// ---------------------------------------------------------------- rmsnorm -> bf16
__global__ __launch_bounds__(256) void rmsnorm_kernel(
    const float* __restrict__ x, const float* __restrict__ w, unsigned short* __restrict__ h) {
    const int row = blockIdx.x;
    const float* xr = x + (size_t)row * D;
    float ss = 0.f;
    for (int d = threadIdx.x; d < D; d += 256) { float v = xr[d]; ss += v * v; }
    const int wave = threadIdx.x >> 6, lane = threadIdx.x & 63;
    __shared__ float red[4];
    float s = wave_sum(ss);
    if (lane == 0) red[wave] = s;
    __syncthreads();
    float tot = red[0] + red[1] + red[2] + red[3];
    float inv = rsqrtf(tot * (1.0f / D) + 1e-6f);
    for (int d = threadIdx.x; d < D; d += 256)
        h[(size_t)row * D + d] = f2bf(xr[d] * inv * w[d]);
}

// ---------------------------------------------------------------- bf16 MFMA GEMM, 128x128, BK=64
// C(MxN) = A(MxK)[bf16] @ W(NxK)^T[bf16]; global_load_lds staging, XOR-swizzled LDS.
// MODE 1: bf16 qkv scatter [3][B,H,T,DH] (q scaled 0.125)
// MODE 3: fp32 atomicAdd (split-K / residual accumulate)
template <int MODE, int SPLITK>
__global__ __launch_bounds__(256) void gemm128(
    const unsigned short* __restrict__ A, const unsigned short* __restrict__ W,
    void* __restrict__ Cv, int M, int N, int K) {
    __shared__ unsigned short As[128 * 64];
    __shared__ unsigned short Ws[128 * 64];
    const int tid  = threadIdx.x;
    const int row0 = blockIdx.y * 128;
    const int col0 = blockIdx.x * 128;
    const int kchunk = K / SPLITK;
    const int kbeg = blockIdx.z * kchunk;
    const int kend = kbeg + kchunk;
    const int wv = tid >> 6, lane = tid & 63;
    const int l15 = lane & 15, quad = lane >> 4;
    const int wm = (wv & 1) * 64, wn = (wv >> 1) * 64;
    const int rb = tid >> 3;       // row within 32-row group, + q*32
    const int sl = tid & 7;        // LDS slot (8-bf16 chunks)

    floatx4 acc[4][4];
    #pragma unroll
    for (int i = 0; i < 4; ++i)
        #pragma unroll
        for (int j = 0; j < 4; ++j) acc[i][j] = (floatx4){0.f, 0.f, 0.f, 0.f};

    for (int k0 = kbeg; k0 < kend; k0 += 64) {
        __syncthreads();
        #pragma unroll
        for (int q = 0; q < 4; ++q) {
            const int r = q * 32 + rb;
            const int gsl = sl ^ (r & 7);           // source chunk for this LDS slot
            gl2lds16(A + (size_t)(row0 + r) * K + k0 + gsl * 8,
                     &As[(q * 256 + wv * 64) * 8]);
            gl2lds16(W + (size_t)(col0 + r) * K + k0 + gsl * 8,
                     &Ws[(q * 256 + wv * 64) * 8]);
        }
        __syncthreads();
        #pragma unroll
        for (int ks = 0; ks < 2; ++ks) {
            short8 af[4], bf[4];
            #pragma unroll
            for (int i = 0; i < 4; ++i) {
                const int r = wm + i * 16 + l15;
                af[i] = *(const short8*)(&As[r * 64 + (((ks * 4 + quad) ^ (r & 7)) * 8)]);
            }
            #pragma unroll
            for (int j = 0; j < 4; ++j) {
                const int r = wn + j * 16 + l15;
                bf[j] = *(const short8*)(&Ws[r * 64 + (((ks * 4 + quad) ^ (r & 7)) * 8)]);
            }
            #pragma unroll
            for (int i = 0; i < 4; ++i)
                #pragma unroll
                for (int j = 0; j < 4; ++j)
                    acc[i][j] = __builtin_amdgcn_mfma_f32_16x16x32_bf16(af[i], bf[j], acc[i][j], 0, 0, 0);
        }
    }

    #pragma unroll
    for (int i = 0; i < 4; ++i) {
        #pragma unroll
        for (int j = 0; j < 4; ++j) {
            const int n = col0 + wn + j * 16 + l15;
            #pragma unroll
            for (int r = 0; r < 4; ++r) {
                const int m = row0 + wm + i * 16 + quad * 4 + r;
                const float v = acc[i][j][r];
                if (MODE == 3) {
                    atomicAdd(&((float*)Cv)[(size_t)m * N + n], v);
                } else { // MODE 1: qkv scatter
                    const int wsel = n / D;
                    const int rr = n - wsel * D;
                    const int hh = rr >> 6, dd = rr & 63;
                    const int b = m >> 10, t = m & 1023;
                    ((unsigned short*)Cv)[(size_t)wsel * (BT * D) +
                        (((size_t)(b * NH + hh)) * TT + t) * DH + dd] =
                        f2bf(wsel == 0 ? v * 0.125f : v);
                }
            }
        }
    }
}

// ---------------------------------------------------------------- fused gate/up/silu GEMM
// tile: 128 M x 64 N (both gate & up), BK=64; global_load_lds staging.
__global__ __launch_bounds__(256) void gateup128(
    const unsigned short* __restrict__ A, const unsigned short* __restrict__ Wg,
    const unsigned short* __restrict__ Wu, unsigned short* __restrict__ gbf, int K) {
    __shared__ unsigned short As[128 * 64];
    __shared__ unsigned short Gs[64 * 64];
    __shared__ unsigned short Us[64 * 64];
    const int tid  = threadIdx.x;
    const int row0 = blockIdx.y * 128;
    const int col0 = blockIdx.x * 64;
    const int wv = tid >> 6, lane = tid & 63;
    const int l15 = lane & 15, quad = lane >> 4;
    const int wm = (wv & 1) * 64, wn = (wv >> 1) * 32;
    const int rb = tid >> 3;
    const int sl = tid & 7;

    floatx4 ag[4][2], au[4][2];
    #pragma unroll
    for (int i = 0; i < 4; ++i)
        #pragma unroll
        for (int j = 0; j < 2; ++j) {
            ag[i][j] = (floatx4){0.f, 0.f, 0.f, 0.f};
            au[i][j] = (floatx4){0.f, 0.f, 0.f, 0.f};
        }

    for (int k0 = 0; k0 < K; k0 += 64) {
        __syncthreads();
        #pragma unroll
        for (int q = 0; q < 4; ++q) {   // A: 1024 chunks
            const int r = q * 32 + rb;
            const int gsl = sl ^ (r & 7);
            gl2lds16(A + (size_t)(row0 + r) * K + k0 + gsl * 8,
                     &As[(q * 256 + wv * 64) * 8]);
        }
        {   // G: 512 chunks, U: 512 chunks (2 iters each)
            #pragma unroll
            for (int q = 0; q < 2; ++q) {
                const int r = q * 32 + rb;
                const int gsl = sl ^ (r & 7);
                gl2lds16(Wg + (size_t)(col0 + r) * K + k0 + gsl * 8,
                         &Gs[(q * 256 + wv * 64) * 8]);
                gl2lds16(Wu + (size_t)(col0 + r) * K + k0 + gsl * 8,
                         &Us[(q * 256 + wv * 64) * 8]);
            }
        }
        __syncthreads();
        #pragma unroll
        for (int ks = 0; ks < 2; ++ks) {
            short8 af[4], bg[2], bu[2];
            #pragma unroll
            for (int i = 0; i < 4; ++i) {
                const int r = wm + i * 16 + l15;
                af[i] = *(const short8*)(&As[r * 64 + (((ks * 4 + quad) ^ (r & 7)) * 8)]);
            }
            #pragma unroll
            for (int j = 0; j < 2; ++j) {
                const int r = wn + j * 16 + l15;
                const int off = r * 64 + (((ks * 4 + quad) ^ (r & 7)) * 8);
                bg[j] = *(const short8*)(&Gs[off]);
                bu[j] = *(const short8*)(&Us[off]);
            }
            #pragma unroll
            for (int i = 0; i < 4; ++i)
                #pragma unroll
                for (int j = 0; j < 2; ++j) {
                    ag[i][j] = __builtin_amdgcn_mfma_f32_16x16x32_bf16(af[i], bg[j], ag[i][j], 0, 0, 0);
                    au[i][j] = __builtin_amdgcn_mfma_f32_16x16x32_bf16(af[i], bu[j], au[i][j], 0, 0, 0);
                }
        }
    }

    #pragma unroll
    for (int i = 0; i < 4; ++i) {
        #pragma unroll
        for (int j = 0; j < 2; ++j) {
            const int n = col0 + wn + j * 16 + l15;
            #pragma unroll
            for (int r = 0; r < 4; ++r) {
                const int m = row0 + wm + i * 16 + quad * 4 + r;
                const float gv = ag[i][j][r], uv = au[i][j][r];
                gbf[(size_t)m * FF + n] = f2bf(gv / (1.f + __expf(-gv)) * uv);
            }
        }
    }
}

// ---------------------------------------------------------------- MFMA flash attention
#define KP 72
__global__ __launch_bounds__(256) void attn_mfma(
    const unsigned short* __restrict__ qkv, unsigned short* __restrict__ obf) {
    const int bh = blockIdx.y;
    const int b = bh / NH, h = bh - b * NH;
    const int qt = blockIdx.x;
    const int q0 = qt * 64;
    const int tid = threadIdx.x;
    const int wv = tid >> 6, lane = tid & 63;
    const int l15 = lane & 15, quad = lane >> 4;

    const unsigned short* Q = qkv + (size_t)bh * TT * DH;
    const unsigned short* K = qkv + (size_t)BT * D + (size_t)bh * TT * DH;
    const unsigned short* V = qkv + 2 * (size_t)BT * D + (size_t)bh * TT * DH;

    __shared__ unsigned short Ks[64 * KP];
    __shared__ unsigned short Vts[64 * KP];
    __shared__ unsigned short Pa[64 * KP];

    short8 qf[2];
    #pragma unroll
    for (int c = 0; c < 2; ++c)
        qf[c] = *(const short8*)(Q + (size_t)(q0 + wv * 16 + l15) * DH + c * 32 + quad * 8);

    floatx4 o_acc[4];
    #pragma unroll
    for (int j = 0; j < 4; ++j) o_acc[j] = (floatx4){0.f, 0.f, 0.f, 0.f};
    float m_run[4] = {-INFINITY, -INFINITY, -INFINITY, -INFINITY};
    float l_run[4] = {0.f, 0.f, 0.f, 0.f};

    for (int kt = 0; kt <= qt; ++kt) {
        __syncthreads();
        {
            const int krow = tid >> 2, kq = tid & 3;
            const unsigned short* kg = K + (size_t)(kt * 64 + krow) * DH + kq * 16;
            ushort8 k0v = *(const ushort8*)(kg);
            ushort8 k1v = *(const ushort8*)(kg + 8);
            *(ushort8*)(&Ks[krow * KP + kq * 16])     = k0v;
            *(ushort8*)(&Ks[krow * KP + kq * 16 + 8]) = k1v;
            const int kp = tid & 31, chunk = tid >> 5;
            const unsigned short* vg = V + (size_t)(kt * 64 + 2 * kp) * DH + chunk * 8;
            ushort8 v0 = *(const ushort8*)(vg);
            ushort8 v1 = *(const ushort8*)(vg + DH);
            #pragma unroll
            for (int j = 0; j < 8; ++j) {
                unsigned int pk = (unsigned int)v0[j] | ((unsigned int)v1[j] << 16);
                *(unsigned int*)(&Vts[(chunk * 8 + j) * KP + 2 * kp]) = pk;
            }
        }
        __syncthreads();

        floatx4 s[4];
        #pragma unroll
        for (int j = 0; j < 4; ++j) {
            short8 kb0 = *(const short8*)(&Ks[(j * 16 + l15) * KP + quad * 8]);
            short8 kb1 = *(const short8*)(&Ks[(j * 16 + l15) * KP + 32 + quad * 8]);
            floatx4 z = (floatx4){0.f, 0.f, 0.f, 0.f};
            z = __builtin_amdgcn_mfma_f32_16x16x32_bf16(qf[0], kb0, z, 0, 0, 0);
            s[j] = __builtin_amdgcn_mfma_f32_16x16x32_bf16(qf[1], kb1, z, 0, 0, 0);
        }
        if (kt == qt) {
            #pragma unroll
            for (int j = 0; j < 4; ++j) {
                const int k_rel = j * 16 + l15;
                #pragma unroll
                for (int r = 0; r < 4; ++r) {
                    const int q_rel = wv * 16 + quad * 4 + r;
                    if (k_rel > q_rel) s[j][r] = -INFINITY;
                }
            }
        }
        #pragma unroll
        for (int r = 0; r < 4; ++r) {
            float mt = fmaxf(fmaxf(s[0][r], s[1][r]), fmaxf(s[2][r], s[3][r]));
            mt = fmaxf(mt, __shfl_xor(mt, 1));
            mt = fmaxf(mt, __shfl_xor(mt, 2));
            mt = fmaxf(mt, __shfl_xor(mt, 4));
            mt = fmaxf(mt, __shfl_xor(mt, 8));
            const float m_new = fmaxf(m_run[r], mt);
            const float alpha = __expf(m_run[r] - m_new);
            float rs = 0.f;
            #pragma unroll
            for (int j = 0; j < 4; ++j) {
                const float p = __expf(s[j][r] - m_new);
                s[j][r] = p;
                rs += p;
            }
            rs += __shfl_xor(rs, 1);
            rs += __shfl_xor(rs, 2);
            rs += __shfl_xor(rs, 4);
            rs += __shfl_xor(rs, 8);
            l_run[r] = l_run[r] * alpha + rs;
            m_run[r] = m_new;
            #pragma unroll
            for (int j = 0; j < 4; ++j) o_acc[j][r] *= alpha;
        }
        #pragma unroll
        for (int j = 0; j < 4; ++j)
            #pragma unroll
            for (int r = 0; r < 4; ++r)
                Pa[(wv * 16 + quad * 4 + r) * KP + j * 16 + l15] = f2bf(s[j][r]);
        short8 pa0 = *(const short8*)(&Pa[(wv * 16 + l15) * KP + quad * 8]);
        short8 pa1 = *(const short8*)(&Pa[(wv * 16 + l15) * KP + 32 + quad * 8]);
        #pragma unroll
        for (int j = 0; j < 4; ++j) {
            short8 vb0 = *(const short8*)(&Vts[(j * 16 + l15) * KP + quad * 8]);
            short8 vb1 = *(const short8*)(&Vts[(j * 16 + l15) * KP + 32 + quad * 8]);
            o_acc[j] = __builtin_amdgcn_mfma_f32_16x16x32_bf16(pa0, vb0, o_acc[j], 0, 0, 0);
            o_acc[j] = __builtin_amdgcn_mfma_f32_16x16x32_bf16(pa1, vb1, o_acc[j], 0, 0, 0);
        }
    }
    #pragma unroll
    for (int j = 0; j < 4; ++j) {
        #pragma unroll
        for (int r = 0; r < 4; ++r) {
            const int t = q0 + wv * 16 + quad * 4 + r;
            const int ch = h * DH + j * 16 + l15;
            obf[((size_t)(b * TT + t)) * D + ch] = f2bf(o_acc[j][r] / l_run[r]);
        }
    }
}

// ---------------------------------------------------------------- final norm (last tokens)
__global__ __launch_bounds__(256) void final_norm_kernel(
    const float* __restrict__ x, const float* __restrict__ w, float* __restrict__ last) {
    const int b = blockIdx.x;
    const float* xr = x + ((size_t)(b * TT + (TT - 1))) * D;
    float ss = 0.f;
    for (int d = threadIdx.x; d < D; d += 256) { float v = xr[d]; ss += v * v; }
    const int wave = threadIdx.x >> 6, lane = threadIdx.x & 63;
    __shared__ float red[4];
    float s = wave_sum(ss);
    if (lane == 0) red[wave] = s;
    __syncthreads();
    float tot = red[0] + red[1] + red[2] + red[3];
    float inv = rsqrtf(tot * (1.0f / D) + 1e-6f);
    for (int d = threadIdx.x; d < D; d += 256)
        last[(size_t)b * D + d] = xr[d] * inv * w[d];
}

// ---------------------------------------------------------------- heads
__global__ __launch_bounds__(256) void heads_kernel(
    const float* __restrict__ last, const float* __restrict__ hw, float* __restrict__ out) {
    const int gw = (blockIdx.x * 256 + threadIdx.x) >> 6;
    const int lane = threadIdx.x & 63;
    const int s = gw >> 10, v = gw & 1023;
    const float* w = hw + (size_t)gw * D;
    float a0 = 0.f, a1 = 0.f;
    for (int d = lane; d < D; d += 64) {
        const float ww = w[d];
        a0 = fmaf(ww, last[d], a0);
        a1 = fmaf(ww, last[D + d], a1);
    }
    a0 = wave_sum(a0);
    a1 = wave_sum(a1);
    if (lane == 0) {
        out[((size_t)s * BB + 0) * NV + v] = a0;
        out[((size_t)s * BB + 1) * NV + v] = a1;
    }
}

// ---------------------------------------------------------------- launcher
extern "C" void kernel_launch(void* const* d_in, const int* in_sizes, int n_in,
                              void* d_out, int out_size, void* d_ws, size_t ws_size,
                              hipStream_t stream) {
    const int*   prev_tokens = (const int*)  d_in[0];
    const int*   positions   = (const int*)  d_in[1];
    const float* intent      = (const float*)d_in[2];
    const float* rvq         = (const float*)d_in[3];
    const float* pos_emb     = (const float*)d_in[4];
    const float* norm1_w     = (const float*)d_in[5];
    const float* norm2_w     = (const float*)d_in[6];
    const float* qkv_w       = (const float*)d_in[7];
    const float* proj_w      = (const float*)d_in[8];
    const float* gate_w      = (const float*)d_in[9];
    const float* up_w        = (const float*)d_in[10];
    const float* down_w      = (const float*)d_in[11];
    const float* normf_w     = (const float*)d_in[12];
    const float* heads_w     = (const float*)d_in[13];
    float* out = (float*)d_out;

    char* base = (char*)d_ws;
    float* x   = (float*)base;                       base += (size_t)BT * D * 4;
    float* last= (float*)base;                       base += 4096;
    unsigned short* hbf    = (unsigned short*)base;  base += (size_t)BT * D * 2;
    unsigned short* qkvbf  = (unsigned short*)base;  base += (size_t)3 * BT * D * 2;
    unsigned short* obf    = (unsigned short*)base;  base += (size_t)BT * D * 2;
    unsigned short* gbf    = (unsigned short*)base;  base += (size_t)BT * FF * 2;
    // bf16 weight caches
    unsigned short* wqkv = (unsigned short*)base;    base += (size_t)LAYERS * 3 * D * D * 2;
    unsigned short* wproj= (unsigned short*)base;    base += (size_t)LAYERS * D * D * 2;
    unsigned short* wgate= (unsigned short*)base;    base += (size_t)LAYERS * FF * D * 2;
    unsigned short* wup  = (unsigned short*)base;    base += (size_t)LAYERS * FF * D * 2;
    unsigned short* wdown= (unsigned short*)base;    base += (size_t)LAYERS * D * FF * 2;

    // convert weights fp32 -> bf16 (per launch; deterministic)
    {
        const int n_qkv  = LAYERS * 3 * D * D / 8;
        const int n_proj = LAYERS * D * D / 8;
        const int n_ff   = LAYERS * FF * D / 8;
        cvt_bf16_kernel<<<(n_qkv  + 255) / 256, 256, 0, stream>>>(qkv_w,  wqkv,  n_qkv);
        cvt_bf16_kernel<<<(n_proj + 255) / 256, 256, 0, stream>>>(proj_w, wproj, n_proj);
        cvt_bf16_kernel<<<(n_ff   + 255) / 256, 256, 0, stream>>>(gate_w, wgate, n_ff);
        cvt_bf16_kernel<<<(n_ff   + 255) / 256, 256, 0, stream>>>(up_w,   wup,   n_ff);
        cvt_bf16_kernel<<<(n_ff   + 255) / 256, 256, 0, stream>>>(down_w, wdown, n_ff);
    }

    embed_kernel<<<BT, 256, 0, stream>>>(prev_tokens, positions, intent, rvq, pos_emb, x);

    for (int l = 0; l < LAYERS; ++l) {
        rmsnorm_kernel<<<BT, 256, 0, stream>>>(x, norm1_w + l * D, hbf);
        gemm128<1, 1><<<dim3(3 * D / 128, BT / 128, 1), 256, 0, stream>>>(
            hbf, wqkv + (size_t)l * 3 * D * D, qkvbf, BT, 3 * D, D);
        attn_mfma<<<dim3(TT / 64, BB * NH), 256, 0, stream>>>(qkvbf, obf);
        gemm128<3, 2><<<dim3(D / 128, BT / 128, 2), 256, 0, stream>>>(
            obf, wproj + (size_t)l * D * D, x, BT, D, D);
        rmsnorm_kernel<<<BT, 256, 0, stream>>>(x, norm2_w + l * D, hbf);
        gateup128<<<dim3(FF / 64, BT / 128), 256, 0, stream>>>(
            hbf, wgate + (size_t)l * FF * D, wup + (size_t)l * FF * D, gbf, D);
        gemm128<3, 4><<<dim3(D / 128, BT / 128, 4), 256, 0, stream>>>(
            gbf, wdown + (size_t)l * D * FF, x, BT, D, FF);
    }

    final_norm_kernel<<<2, 256, 0, stream>>>(x, normf_w, last);
    heads_kernel<<<(NS * NV * 64) / 256, 256, 0, stream>>>(last, heads_w, out);
}